// Round 2
// baseline (1111.655 us; speedup 1.0000x reference)
//
#include <hip/hip_runtime.h>
#include <hip/hip_bf16.h>

#define NN 50000
#define NE 800000
#define HD 128
#define BN_EPS 1e-5f

// ---------------- zero small stats region ----------------
__global__ void k_zero(float* __restrict__ p) {
    p[blockIdx.x * 256 + threadIdx.x] = 0.f;
}

// ---------------- f32 copy (h = z before scatter) ----------------
__global__ void k_copy(const float* __restrict__ a, float* __restrict__ b) {
    const int i = (blockIdx.x * 256 + threadIdx.x) * 4;
    *(float4*)(b + i) = *(const float4*)(a + i);
}

// ---------------- edge scatter-add: h[dst] += z[src] ----------------
__global__ void k_scatter(const float* __restrict__ Z, const int* __restrict__ src,
                          const int* __restrict__ dst, float* __restrict__ Hb) {
    const int e = blockIdx.x * 2 + (threadIdx.x >> 7);
    const int d = threadIdx.x & 127;
    const int s = src[e];
    const int t = dst[e];
    atomicAdd(&Hb[(size_t)t * HD + d], Z[(size_t)s * HD + d]);
}

// ---------------- fp32 GEMM: C = act(A @ W + b), A:(NN,128) W:(128,128) ----------------
template <int ACT>
__global__ __launch_bounds__(256) void k_gemm(const float* __restrict__ A,
                                              const float* __restrict__ W,
                                              const float* __restrict__ bias,
                                              float* __restrict__ C) {
    __shared__ float Al[32][HD];  // 16 KB
    const int tid = threadIdx.x;
    const int tx = tid & 31, ty = tid >> 5;
    const float4 bv = *(const float4*)&bias[tx * 4];

    const int ntiles = (NN + 31) / 32;
    for (int tile = blockIdx.x; tile < ntiles; tile += gridDim.x) {
        const int row0 = tile * 32;
        __syncthreads();
#pragma unroll
        for (int i = tid; i < 32 * HD / 4; i += 256) {
            const int r = i >> 5, c4 = (i & 31) * 4;
            const int row = row0 + r;
            float4 v = make_float4(0.f, 0.f, 0.f, 0.f);
            if (row < NN) v = *(const float4*)&A[(size_t)row * HD + c4];
            *(float4*)&Al[r][c4] = v;
        }
        __syncthreads();
        float acc[4][4] = {};
#pragma unroll 4
        for (int k = 0; k < HD; ++k) {
            const float4 wv = *(const float4*)&W[k * HD + tx * 4];
#pragma unroll
            for (int r = 0; r < 4; ++r) {
                const float a = Al[ty * 4 + r][k];
                acc[r][0] = fmaf(a, wv.x, acc[r][0]);
                acc[r][1] = fmaf(a, wv.y, acc[r][1]);
                acc[r][2] = fmaf(a, wv.z, acc[r][2]);
                acc[r][3] = fmaf(a, wv.w, acc[r][3]);
            }
        }
#pragma unroll
        for (int r = 0; r < 4; ++r) {
            const int row = row0 + ty * 4 + r;
            if (row < NN) {
                float4 v;
                v.x = acc[r][0] + bv.x;
                v.y = acc[r][1] + bv.y;
                v.z = acc[r][2] + bv.z;
                v.w = acc[r][3] + bv.w;
                if (ACT) {
                    v.x = fmaxf(v.x, 0.f); v.y = fmaxf(v.y, 0.f);
                    v.z = fmaxf(v.z, 0.f); v.w = fmaxf(v.w, 0.f);
                }
                *(float4*)&C[(size_t)row * HD + tx * 4] = v;
            }
        }
    }
}

// ---------------- per-column sum / sumsq ----------------
__global__ void k_colstats(const float* __restrict__ X, float* __restrict__ sum,
                           float* __restrict__ sumsq) {
    __shared__ float sh[128], shq[128];
    const int col = threadIdx.x & 127, half = threadIdx.x >> 7;
    const int r0 = blockIdx.x * 256;
    const int r1 = min(r0 + 256, NN);
    float s = 0.f, q = 0.f;
    for (int r = r0 + half; r < r1; r += 2) {
        const float v = X[(size_t)r * HD + col];
        s += v;
        q = fmaf(v, v, q);
    }
    if (half) { sh[col] = s; shq[col] = q; }
    __syncthreads();
    if (!half) {
        atomicAdd(&sum[col], s + sh[col]);
        atomicAdd(&sumsq[col], q + shq[col]);
    }
}

// ---------------- BN finalize: scale/shift per column ----------------
__global__ void k_bnfin(const float* __restrict__ sum, const float* __restrict__ sumsq,
                        const float* __restrict__ gamma, const float* __restrict__ beta,
                        float* __restrict__ scale, float* __restrict__ shift) {
    const int c = threadIdx.x;
    const float mean = sum[c] * (1.f / NN);
    const float var = sumsq[c] * (1.f / NN) - mean * mean;
    const float sc = gamma[c] * rsqrtf(var + BN_EPS);
    scale[c] = sc;
    shift[c] = beta[c] - mean * sc;
}

// ---------------- BN apply (+ optional PReLU), in-place capable ----------------
template <int PRELU>
__global__ void k_bnapply(const float* __restrict__ X, const float* __restrict__ scale,
                          const float* __restrict__ shift, float* __restrict__ Y,
                          const float* __restrict__ pa) {
    const int i = blockIdx.x * 256 + threadIdx.x;
    const int c = i & 127;
    float v = fmaf(X[i], scale[c], shift[c]);
    if (PRELU) {
        const float a = pa[0];
        if (v < 0.f) v = a * v;
    }
    Y[i] = v;
}

extern "C" void kernel_launch(void* const* d_in, const int* in_sizes, int n_in,
                              void* d_out, int out_size, void* d_ws, size_t ws_size,
                              hipStream_t stream) {
    const float* x = (const float*)d_in[0];
    const int* ei = (const int*)d_in[1];
    const float* w0a = (const float*)d_in[2];
    const float* b0a = (const float*)d_in[3];
    const float* w0b = (const float*)d_in[4];
    const float* b0b = (const float*)d_in[5];
    const float* w1a = (const float*)d_in[6];
    const float* b1a = (const float*)d_in[7];
    const float* w1b = (const float*)d_in[8];
    const float* b1b = (const float*)d_in[9];
    const float* bng = (const float*)d_in[10];
    const float* bnb = (const float*)d_in[11];
    const float* pw  = (const float*)d_in[12];
    const float* pb  = (const float*)d_in[13];
    const float* pbng = (const float*)d_in[14];
    const float* pbnb = (const float*)d_in[15];
    const float* pa = (const float*)d_in[16];

    float* outZ = (float*)d_out;                    // (NN,128) f32
    float* outP = outZ + (size_t)NN * HD;           // (NN,128) f32

    float* ws = (float*)d_ws;
    float* bufH = ws;                               // (NN,128) f32 — aggregate
    float* bufT = bufH + (size_t)NN * HD;           // (NN,128) f32 — MLP mid
    float* st = bufT + (size_t)NN * HD;             // 1024 floats of stats

    const int* srcv = ei;
    const int* dstv = ei + NE;

    const int ELW = (NN * HD) / (256 * 4);          // 6250 blocks, f32x4 elementwise
    const int EL1 = (NN * HD) / 256;                // 25000 blocks, scalar elementwise
    const int SCAT = NE / 2;                        // 400000 blocks
    const int CST = (NN + 255) / 256;               // 196 blocks

    k_zero<<<4, 256, 0, stream>>>(st);

    // ---- GIN layer 0: h = x + scatter(x); z1 = relu(relu(h@w0a+b0a)@w0b+b0b) ----
    k_copy<<<ELW, 256, 0, stream>>>(x, bufH);
    k_scatter<<<SCAT, 256, 0, stream>>>(x, srcv, dstv, bufH);
    k_gemm<1><<<512, 256, 0, stream>>>(bufH, w0a, b0a, bufT);
    k_gemm<1><<<512, 256, 0, stream>>>(bufT, w0b, b0b, outZ);   // z1 staged in outZ

    // ---- GIN layer 1 ----
    k_copy<<<ELW, 256, 0, stream>>>(outZ, bufH);
    k_scatter<<<SCAT, 256, 0, stream>>>(outZ, srcv, dstv, bufH);
    k_gemm<1><<<512, 256, 0, stream>>>(bufH, w1a, b1a, bufT);
    k_gemm<1><<<512, 256, 0, stream>>>(bufT, w1b, b1b, outZ);   // z2 overwrites z1

    // ---- encoder BatchNorm -> z output (in place) ----
    k_colstats<<<CST, 256, 0, stream>>>(outZ, st + 0, st + 128);
    k_bnfin<<<1, 128, 0, stream>>>(st + 0, st + 128, bng, bnb, st + 256, st + 384);
    k_bnapply<0><<<EL1, 256, 0, stream>>>(outZ, st + 256, st + 384, outZ, pa);

    // ---- projection head: linear -> BN -> PReLU -> p output (in place) ----
    k_gemm<0><<<512, 256, 0, stream>>>(outZ, pw, pb, outP);
    k_colstats<<<CST, 256, 0, stream>>>(outP, st + 512, st + 640);
    k_bnfin<<<1, 128, 0, stream>>>(st + 512, st + 640, pbng, pbnb, st + 768, st + 896);
    k_bnapply<1><<<EL1, 256, 0, stream>>>(outP, st + 768, st + 896, outP, pa);
}

// Round 3
// 811.796 us; speedup vs baseline: 1.3694x; 1.3694x over previous
//
#include <hip/hip_runtime.h>
#include <hip/hip_bf16.h>

#define NN 50000
#define NE 800000
#define HD 128
#define BN_EPS 1e-5f

// ---------------- zero helpers ----------------
__global__ void k_zero_f(float* __restrict__ p, int n) {
    const int i = blockIdx.x * 256 + threadIdx.x;
    if (i < n) p[i] = 0.f;
}
__global__ void k_zero_i(int* __restrict__ p, int n) {
    const int i = blockIdx.x * 256 + threadIdx.x;
    if (i < n) p[i] = 0;
}

// ---------------- CSR build: histogram of dst ----------------
__global__ void k_hist(const int* __restrict__ dst, int* __restrict__ deg) {
    const int e = blockIdx.x * 256 + threadIdx.x;
    atomicAdd(&deg[dst[e]], 1);
}

// ---------------- CSR build: exclusive scan (1 block, 256 threads) ----------------
__global__ void k_scan(const int* __restrict__ deg, int* __restrict__ rowptr,
                       int* __restrict__ cur) {
    __shared__ int csum[256];
    const int t = threadIdx.x;
    const int CH = (NN + 255) / 256;  // 196
    const int lo = t * CH, hi = min(lo + CH, NN);
    int s = 0;
    for (int i = lo; i < hi; ++i) s += deg[i];
    csum[t] = s;
    __syncthreads();
    if (t == 0) {
        int run = 0;
        for (int i = 0; i < 256; ++i) { const int v = csum[i]; csum[i] = run; run += v; }
    }
    __syncthreads();
    int run = csum[t];
    for (int i = lo; i < hi; ++i) {
        rowptr[i] = run;
        cur[i] = run;
        run += deg[i];
    }
    if (t == 255) rowptr[NN] = run;
}

// ---------------- CSR build: fill edge sources ----------------
__global__ void k_fill(const int* __restrict__ src, const int* __restrict__ dst,
                       int* __restrict__ cur, int* __restrict__ esrc) {
    const int e = blockIdx.x * 256 + threadIdx.x;
    const int p = atomicAdd(&cur[dst[e]], 1);
    esrc[p] = src[e];
}

// ---------------- gather-aggregate: H[i] = Z[i] + sum_{j->i} Z[j] ----------------
__global__ __launch_bounds__(256) void k_agg(const float* __restrict__ Z,
                                             const int* __restrict__ rowptr,
                                             const int* __restrict__ esrc,
                                             float* __restrict__ H) {
    const int node = blockIdx.x * 2 + (threadIdx.x >> 7);
    const int col = threadIdx.x & 127;
    const int start = rowptr[node], end = rowptr[node + 1];
    float acc = Z[(size_t)node * HD + col];
    int k = start;
    for (; k + 1 < end; k += 2) {
        const int s0 = esrc[k], s1 = esrc[k + 1];
        const float v0 = Z[(size_t)s0 * HD + col];
        const float v1 = Z[(size_t)s1 * HD + col];
        acc += v0 + v1;
    }
    if (k < end) acc += Z[(size_t)esrc[k] * HD + col];
    H[(size_t)node * HD + col] = acc;
}

// ---------------- fp32 GEMM: C = act(A @ W + b), A:(NN,128) W:(128,128) ----------------
template <int ACT>
__global__ __launch_bounds__(256) void k_gemm(const float* __restrict__ A,
                                              const float* __restrict__ W,
                                              const float* __restrict__ bias,
                                              float* __restrict__ C) {
    __shared__ float Al[32][HD];  // 16 KB
    const int tid = threadIdx.x;
    const int tx = tid & 31, ty = tid >> 5;
    const float4 bv = *(const float4*)&bias[tx * 4];

    const int ntiles = (NN + 31) / 32;
    for (int tile = blockIdx.x; tile < ntiles; tile += gridDim.x) {
        const int row0 = tile * 32;
        __syncthreads();
#pragma unroll
        for (int i = tid; i < 32 * HD / 4; i += 256) {
            const int r = i >> 5, c4 = (i & 31) * 4;
            const int row = row0 + r;
            float4 v = make_float4(0.f, 0.f, 0.f, 0.f);
            if (row < NN) v = *(const float4*)&A[(size_t)row * HD + c4];
            *(float4*)&Al[r][c4] = v;
        }
        __syncthreads();
        float acc[4][4] = {};
#pragma unroll 4
        for (int k = 0; k < HD; ++k) {
            const float4 wv = *(const float4*)&W[k * HD + tx * 4];
#pragma unroll
            for (int r = 0; r < 4; ++r) {
                const float a = Al[ty * 4 + r][k];
                acc[r][0] = fmaf(a, wv.x, acc[r][0]);
                acc[r][1] = fmaf(a, wv.y, acc[r][1]);
                acc[r][2] = fmaf(a, wv.z, acc[r][2]);
                acc[r][3] = fmaf(a, wv.w, acc[r][3]);
            }
        }
#pragma unroll
        for (int r = 0; r < 4; ++r) {
            const int row = row0 + ty * 4 + r;
            if (row < NN) {
                float4 v;
                v.x = acc[r][0] + bv.x;
                v.y = acc[r][1] + bv.y;
                v.z = acc[r][2] + bv.z;
                v.w = acc[r][3] + bv.w;
                if (ACT) {
                    v.x = fmaxf(v.x, 0.f); v.y = fmaxf(v.y, 0.f);
                    v.z = fmaxf(v.z, 0.f); v.w = fmaxf(v.w, 0.f);
                }
                *(float4*)&C[(size_t)row * HD + tx * 4] = v;
            }
        }
    }
}

// ---------------- per-column sum / sumsq ----------------
__global__ void k_colstats(const float* __restrict__ X, float* __restrict__ sum,
                           float* __restrict__ sumsq) {
    __shared__ float sh[128], shq[128];
    const int col = threadIdx.x & 127, half = threadIdx.x >> 7;
    const int r0 = blockIdx.x * 256;
    const int r1 = min(r0 + 256, NN);
    float s = 0.f, q = 0.f;
    for (int r = r0 + half; r < r1; r += 2) {
        const float v = X[(size_t)r * HD + col];
        s += v;
        q = fmaf(v, v, q);
    }
    if (half) { sh[col] = s; shq[col] = q; }
    __syncthreads();
    if (!half) {
        atomicAdd(&sum[col], s + sh[col]);
        atomicAdd(&sumsq[col], q + shq[col]);
    }
}

// ---------------- BN finalize ----------------
__global__ void k_bnfin(const float* __restrict__ sum, const float* __restrict__ sumsq,
                        const float* __restrict__ gamma, const float* __restrict__ beta,
                        float* __restrict__ scale, float* __restrict__ shift) {
    const int c = threadIdx.x;
    const float mean = sum[c] * (1.f / NN);
    const float var = sumsq[c] * (1.f / NN) - mean * mean;
    const float sc = gamma[c] * rsqrtf(var + BN_EPS);
    scale[c] = sc;
    shift[c] = beta[c] - mean * sc;
}

// ---------------- BN apply (+ optional PReLU), in-place capable ----------------
template <int PRELU>
__global__ void k_bnapply(const float* __restrict__ X, const float* __restrict__ scale,
                          const float* __restrict__ shift, float* __restrict__ Y,
                          const float* __restrict__ pa) {
    const int i = blockIdx.x * 256 + threadIdx.x;
    const int c = i & 127;
    float v = fmaf(X[i], scale[c], shift[c]);
    if (PRELU) {
        const float a = pa[0];
        if (v < 0.f) v = a * v;
    }
    Y[i] = v;
}

extern "C" void kernel_launch(void* const* d_in, const int* in_sizes, int n_in,
                              void* d_out, int out_size, void* d_ws, size_t ws_size,
                              hipStream_t stream) {
    const float* x = (const float*)d_in[0];
    const int* ei = (const int*)d_in[1];
    const float* w0a = (const float*)d_in[2];
    const float* b0a = (const float*)d_in[3];
    const float* w0b = (const float*)d_in[4];
    const float* b0b = (const float*)d_in[5];
    const float* w1a = (const float*)d_in[6];
    const float* b1a = (const float*)d_in[7];
    const float* w1b = (const float*)d_in[8];
    const float* b1b = (const float*)d_in[9];
    const float* bng = (const float*)d_in[10];
    const float* bnb = (const float*)d_in[11];
    const float* pw  = (const float*)d_in[12];
    const float* pb  = (const float*)d_in[13];
    const float* pbng = (const float*)d_in[14];
    const float* pbnb = (const float*)d_in[15];
    const float* pa = (const float*)d_in[16];

    float* outZ = (float*)d_out;                    // (NN,128) f32 — z
    float* outP = outZ + (size_t)NN * HD;           // (NN,128) f32 — p (also MLP temp)

    float* ws = (float*)d_ws;
    float* bufH = ws;                               // (NN,128) f32 — aggregate
    float* st = bufH + (size_t)NN * HD;             // 1024 floats of stats
    int* deg = (int*)(st + 1024);                   // NN
    int* rowptr = deg + NN;                         // NN+1 (+pad)
    int* cur = rowptr + NN + 64;                    // NN
    int* esrc = cur + NN;                           // NE

    const int* srcv = ei;
    const int* dstv = ei + NE;

    const int EB = NE / 256;                        // 3125 edge blocks
    const int NB = (NN + 255) / 256;                // 196 node blocks
    const int EL1 = (NN * HD) / 256;                // 25000 elementwise blocks

    // ---- CSR build (dst-sorted) + stat zeroing ----
    k_zero_f<<<4, 256, 0, stream>>>(st, 1024);
    k_zero_i<<<NB, 256, 0, stream>>>(deg, NN);
    k_hist<<<EB, 256, 0, stream>>>(dstv, deg);
    k_scan<<<1, 256, 0, stream>>>(deg, rowptr, cur);
    k_fill<<<EB, 256, 0, stream>>>(srcv, dstv, cur, esrc);

    // ---- GIN layer 0 ----
    k_agg<<<NN / 2, 256, 0, stream>>>(x, rowptr, esrc, bufH);
    k_gemm<1><<<512, 256, 0, stream>>>(bufH, w0a, b0a, outP);
    k_gemm<1><<<512, 256, 0, stream>>>(outP, w0b, b0b, outZ);   // z1

    // ---- GIN layer 1 ----
    k_agg<<<NN / 2, 256, 0, stream>>>(outZ, rowptr, esrc, bufH);
    k_gemm<1><<<512, 256, 0, stream>>>(bufH, w1a, b1a, outP);
    k_gemm<1><<<512, 256, 0, stream>>>(outP, w1b, b1b, outZ);   // z2

    // ---- encoder BatchNorm -> z output (in place) ----
    k_colstats<<<NB, 256, 0, stream>>>(outZ, st + 0, st + 128);
    k_bnfin<<<1, 128, 0, stream>>>(st + 0, st + 128, bng, bnb, st + 256, st + 384);
    k_bnapply<0><<<EL1, 256, 0, stream>>>(outZ, st + 256, st + 384, outZ, pa);

    // ---- projection head: linear -> BN -> PReLU -> p output (in place) ----
    k_gemm<0><<<512, 256, 0, stream>>>(outZ, pw, pb, outP);
    k_colstats<<<NB, 256, 0, stream>>>(outP, st + 512, st + 640);
    k_bnfin<<<1, 128, 0, stream>>>(st + 512, st + 640, pbng, pbnb, st + 768, st + 896);
    k_bnapply<1><<<EL1, 256, 0, stream>>>(outP, st + 768, st + 896, outP, pa);
}

// Round 4
// 693.983 us; speedup vs baseline: 1.6018x; 1.1698x over previous
//
#include <hip/hip_runtime.h>
#include <hip/hip_bf16.h>

#define NN 50000
#define NE 800000
#define HD 128
#define BN_EPS 1e-5f
#define NB_SCAN 196  // ceil(NN/256)

// ---------------- zero helpers ----------------
__global__ void k_zero_f(float* __restrict__ p, int n) {
    const int i = blockIdx.x * 256 + threadIdx.x;
    if (i < n) p[i] = 0.f;
}
__global__ void k_zero_i(int* __restrict__ p, int n) {
    const int i = blockIdx.x * 256 + threadIdx.x;
    if (i < n) p[i] = 0;
}

// ---------------- CSR build: histogram of dst ----------------
__global__ void k_hist(const int* __restrict__ dst, int* __restrict__ deg) {
    const int e = blockIdx.x * 256 + threadIdx.x;
    atomicAdd(&deg[dst[e]], 1);
}

// ---------------- scan phase A: per-block sums of deg ----------------
__global__ __launch_bounds__(256) void k_blocksum(const int* __restrict__ deg,
                                                  int* __restrict__ bsum) {
    __shared__ int sh[256];
    const int t = threadIdx.x;
    const int i = blockIdx.x * 256 + t;
    sh[t] = (i < NN) ? deg[i] : 0;
    __syncthreads();
#pragma unroll
    for (int s = 128; s > 0; s >>= 1) {
        if (t < s) sh[t] += sh[t + s];
        __syncthreads();
    }
    if (t == 0) bsum[blockIdx.x] = sh[0];
}

// ---------------- scan phase B: exclusive scan of block sums (1 block) ----------------
__global__ __launch_bounds__(256) void k_scanpart(const int* __restrict__ bsum,
                                                  int* __restrict__ bbase) {
    __shared__ int sh[256];
    const int t = threadIdx.x;
    const int v = (t < NB_SCAN) ? bsum[t] : 0;
    sh[t] = v;
    __syncthreads();
#pragma unroll
    for (int s = 1; s < 256; s <<= 1) {
        int add = (t >= s) ? sh[t - s] : 0;
        __syncthreads();
        sh[t] += add;
        __syncthreads();
    }
    if (t < NB_SCAN) bbase[t] = sh[t] - v;  // exclusive
}

// ---------------- scan phase C: local scan + offset -> rowptr, cur ----------------
__global__ __launch_bounds__(256) void k_scanfin(const int* __restrict__ deg,
                                                 const int* __restrict__ bbase,
                                                 int* __restrict__ rowptr,
                                                 int* __restrict__ cur) {
    __shared__ int sh[256];
    const int t = threadIdx.x;
    const int i = blockIdx.x * 256 + t;
    const int v = (i < NN) ? deg[i] : 0;
    sh[t] = v;
    __syncthreads();
#pragma unroll
    for (int s = 1; s < 256; s <<= 1) {
        int add = (t >= s) ? sh[t - s] : 0;
        __syncthreads();
        sh[t] += add;
        __syncthreads();
    }
    const int incl = sh[t] + bbase[blockIdx.x];
    if (i < NN) {
        const int excl = incl - v;
        rowptr[i] = excl;
        cur[i] = excl;
        if (i == NN - 1) rowptr[NN] = incl;
    }
}

// ---------------- CSR build: fill edge sources ----------------
__global__ void k_fill(const int* __restrict__ src, const int* __restrict__ dst,
                       int* __restrict__ cur, int* __restrict__ esrc) {
    const int e = blockIdx.x * 256 + threadIdx.x;
    const int p = atomicAdd(&cur[dst[e]], 1);
    esrc[p] = src[e];
}

// ---------------- gather-aggregate: H[i] = Z[i] + sum_{j->i} Z[j] ----------------
__global__ __launch_bounds__(256) void k_agg(const float* __restrict__ Z,
                                             const int* __restrict__ rowptr,
                                             const int* __restrict__ esrc,
                                             float* __restrict__ H) {
    const int node = blockIdx.x * 2 + (threadIdx.x >> 7);
    const int col = threadIdx.x & 127;
    const int start = rowptr[node], end = rowptr[node + 1];
    float acc = Z[(size_t)node * HD + col];
    int k = start;
    for (; k + 1 < end; k += 2) {
        const int s0 = esrc[k], s1 = esrc[k + 1];
        const float v0 = Z[(size_t)s0 * HD + col];
        const float v1 = Z[(size_t)s1 * HD + col];
        acc += v0 + v1;
    }
    if (k < end) acc += Z[(size_t)esrc[k] * HD + col];
    H[(size_t)node * HD + col] = acc;
}

// ---------------- fp32 GEMM: C = act(A @ W + b), A:(NN,128) W:(128,128) ----------------
template <int ACT>
__global__ __launch_bounds__(256) void k_gemm(const float* __restrict__ A,
                                              const float* __restrict__ W,
                                              const float* __restrict__ bias,
                                              float* __restrict__ C) {
    __shared__ float Al[32][HD];  // 16 KB
    const int tid = threadIdx.x;
    const int tx = tid & 31, ty = tid >> 5;
    const float4 bv = *(const float4*)&bias[tx * 4];

    const int ntiles = (NN + 31) / 32;
    for (int tile = blockIdx.x; tile < ntiles; tile += gridDim.x) {
        const int row0 = tile * 32;
        __syncthreads();
#pragma unroll
        for (int i = tid; i < 32 * HD / 4; i += 256) {
            const int r = i >> 5, c4 = (i & 31) * 4;
            const int row = row0 + r;
            float4 v = make_float4(0.f, 0.f, 0.f, 0.f);
            if (row < NN) v = *(const float4*)&A[(size_t)row * HD + c4];
            *(float4*)&Al[r][c4] = v;
        }
        __syncthreads();
        float acc[4][4] = {};
#pragma unroll 4
        for (int k = 0; k < HD; ++k) {
            const float4 wv = *(const float4*)&W[k * HD + tx * 4];
#pragma unroll
            for (int r = 0; r < 4; ++r) {
                const float a = Al[ty * 4 + r][k];
                acc[r][0] = fmaf(a, wv.x, acc[r][0]);
                acc[r][1] = fmaf(a, wv.y, acc[r][1]);
                acc[r][2] = fmaf(a, wv.z, acc[r][2]);
                acc[r][3] = fmaf(a, wv.w, acc[r][3]);
            }
        }
#pragma unroll
        for (int r = 0; r < 4; ++r) {
            const int row = row0 + ty * 4 + r;
            if (row < NN) {
                float4 v;
                v.x = acc[r][0] + bv.x;
                v.y = acc[r][1] + bv.y;
                v.z = acc[r][2] + bv.z;
                v.w = acc[r][3] + bv.w;
                if (ACT) {
                    v.x = fmaxf(v.x, 0.f); v.y = fmaxf(v.y, 0.f);
                    v.z = fmaxf(v.z, 0.f); v.w = fmaxf(v.w, 0.f);
                }
                *(float4*)&C[(size_t)row * HD + tx * 4] = v;
            }
        }
    }
}

// ---------------- per-column sum / sumsq ----------------
__global__ void k_colstats(const float* __restrict__ X, float* __restrict__ sum,
                           float* __restrict__ sumsq) {
    __shared__ float sh[128], shq[128];
    const int col = threadIdx.x & 127, half = threadIdx.x >> 7;
    const int r0 = blockIdx.x * 256;
    const int r1 = min(r0 + 256, NN);
    float s = 0.f, q = 0.f;
    for (int r = r0 + half; r < r1; r += 2) {
        const float v = X[(size_t)r * HD + col];
        s += v;
        q = fmaf(v, v, q);
    }
    if (half) { sh[col] = s; shq[col] = q; }
    __syncthreads();
    if (!half) {
        atomicAdd(&sum[col], s + sh[col]);
        atomicAdd(&sumsq[col], q + shq[col]);
    }
}

// ---------------- BN finalize ----------------
__global__ void k_bnfin(const float* __restrict__ sum, const float* __restrict__ sumsq,
                        const float* __restrict__ gamma, const float* __restrict__ beta,
                        float* __restrict__ scale, float* __restrict__ shift) {
    const int c = threadIdx.x;
    const float mean = sum[c] * (1.f / NN);
    const float var = sumsq[c] * (1.f / NN) - mean * mean;
    const float sc = gamma[c] * rsqrtf(var + BN_EPS);
    scale[c] = sc;
    shift[c] = beta[c] - mean * sc;
}

// ---------------- BN apply (+ optional PReLU), in-place capable ----------------
template <int PRELU>
__global__ void k_bnapply(const float* __restrict__ X, const float* __restrict__ scale,
                          const float* __restrict__ shift, float* __restrict__ Y,
                          const float* __restrict__ pa) {
    const int i = blockIdx.x * 256 + threadIdx.x;
    const int c = i & 127;
    float v = fmaf(X[i], scale[c], shift[c]);
    if (PRELU) {
        const float a = pa[0];
        if (v < 0.f) v = a * v;
    }
    Y[i] = v;
}

extern "C" void kernel_launch(void* const* d_in, const int* in_sizes, int n_in,
                              void* d_out, int out_size, void* d_ws, size_t ws_size,
                              hipStream_t stream) {
    const float* x = (const float*)d_in[0];
    const int* ei = (const int*)d_in[1];
    const float* w0a = (const float*)d_in[2];
    const float* b0a = (const float*)d_in[3];
    const float* w0b = (const float*)d_in[4];
    const float* b0b = (const float*)d_in[5];
    const float* w1a = (const float*)d_in[6];
    const float* b1a = (const float*)d_in[7];
    const float* w1b = (const float*)d_in[8];
    const float* b1b = (const float*)d_in[9];
    const float* bng = (const float*)d_in[10];
    const float* bnb = (const float*)d_in[11];
    const float* pw  = (const float*)d_in[12];
    const float* pb  = (const float*)d_in[13];
    const float* pbng = (const float*)d_in[14];
    const float* pbnb = (const float*)d_in[15];
    const float* pa = (const float*)d_in[16];

    float* outZ = (float*)d_out;                    // (NN,128) f32 — z
    float* outP = outZ + (size_t)NN * HD;           // (NN,128) f32 — p (also MLP temp)

    float* ws = (float*)d_ws;
    float* bufH = ws;                               // (NN,128) f32 — aggregate
    float* st = bufH + (size_t)NN * HD;             // 1024 floats of stats
    int* deg = (int*)(st + 1024);                   // NN
    int* rowptr = deg + NN;                         // NN+1 (+pad)
    int* cur = rowptr + NN + 64;                    // NN
    int* esrc = cur + NN;                           // NE
    int* bsum = esrc + NE;                          // 256
    int* bbase = bsum + 256;                        // 256

    const int* srcv = ei;
    const int* dstv = ei + NE;

    const int EB = NE / 256;                        // 3125 edge blocks
    const int NB = NB_SCAN;                         // 196 node blocks
    const int EL1 = (NN * HD) / 256;                // 25000 elementwise blocks

    // ---- CSR build (dst-sorted) + stat zeroing ----
    k_zero_f<<<4, 256, 0, stream>>>(st, 1024);
    k_zero_i<<<NB, 256, 0, stream>>>(deg, NN);
    k_hist<<<EB, 256, 0, stream>>>(dstv, deg);
    k_blocksum<<<NB, 256, 0, stream>>>(deg, bsum);
    k_scanpart<<<1, 256, 0, stream>>>(bsum, bbase);
    k_scanfin<<<NB, 256, 0, stream>>>(deg, bbase, rowptr, cur);
    k_fill<<<EB, 256, 0, stream>>>(srcv, dstv, cur, esrc);

    // ---- GIN layer 0 ----
    k_agg<<<NN / 2, 256, 0, stream>>>(x, rowptr, esrc, bufH);
    k_gemm<1><<<512, 256, 0, stream>>>(bufH, w0a, b0a, outP);
    k_gemm<1><<<512, 256, 0, stream>>>(outP, w0b, b0b, outZ);   // z1

    // ---- GIN layer 1 ----
    k_agg<<<NN / 2, 256, 0, stream>>>(outZ, rowptr, esrc, bufH);
    k_gemm<1><<<512, 256, 0, stream>>>(bufH, w1a, b1a, outP);
    k_gemm<1><<<512, 256, 0, stream>>>(outP, w1b, b1b, outZ);   // z2

    // ---- encoder BatchNorm -> z output (in place) ----
    k_colstats<<<NB, 256, 0, stream>>>(outZ, st + 0, st + 128);
    k_bnfin<<<1, 128, 0, stream>>>(st + 0, st + 128, bng, bnb, st + 256, st + 384);
    k_bnapply<0><<<EL1, 256, 0, stream>>>(outZ, st + 256, st + 384, outZ, pa);

    // ---- projection head: linear -> BN -> PReLU -> p output (in place) ----
    k_gemm<0><<<512, 256, 0, stream>>>(outZ, pw, pb, outP);
    k_colstats<<<NB, 256, 0, stream>>>(outP, st + 512, st + 640);
    k_bnfin<<<1, 128, 0, stream>>>(st + 512, st + 640, pbng, pbnb, st + 768, st + 896);
    k_bnapply<1><<<EL1, 256, 0, stream>>>(outP, st + 768, st + 896, outP, pa);
}

// Round 6
// 615.046 us; speedup vs baseline: 1.8074x; 1.1283x over previous
//
#include <hip/hip_runtime.h>
#include <hip/hip_bf16.h>

#define NN 50000
#define NE 800000
#define HD 128
#define BN_EPS 1e-5f
#define NB_SCAN 196  // ceil(NN/256)

typedef __attribute__((ext_vector_type(8))) __bf16 bf16x8;
typedef __attribute__((ext_vector_type(4))) float floatx4;

// ---------------- zero helpers ----------------
__global__ void k_zero_f(float* __restrict__ p, int n) {
    const int i = blockIdx.x * 256 + threadIdx.x;
    if (i < n) p[i] = 0.f;
}
__global__ void k_zero_i(int* __restrict__ p, int n) {
    const int i = blockIdx.x * 256 + threadIdx.x;
    if (i < n) p[i] = 0;
}

// ---------------- CSR build: histogram of dst ----------------
__global__ void k_hist(const int* __restrict__ dst, int* __restrict__ deg) {
    const int e = blockIdx.x * 256 + threadIdx.x;
    atomicAdd(&deg[dst[e]], 1);
}

// ---------------- scan phase A: per-block sums of deg ----------------
__global__ __launch_bounds__(256) void k_blocksum(const int* __restrict__ deg,
                                                  int* __restrict__ bsum) {
    __shared__ int sh[256];
    const int t = threadIdx.x;
    const int i = blockIdx.x * 256 + t;
    sh[t] = (i < NN) ? deg[i] : 0;
    __syncthreads();
#pragma unroll
    for (int s = 128; s > 0; s >>= 1) {
        if (t < s) sh[t] += sh[t + s];
        __syncthreads();
    }
    if (t == 0) bsum[blockIdx.x] = sh[0];
}

// ---------------- scan phase B: exclusive scan of block sums (1 block) ----------------
__global__ __launch_bounds__(256) void k_scanpart(const int* __restrict__ bsum,
                                                  int* __restrict__ bbase) {
    __shared__ int sh[256];
    const int t = threadIdx.x;
    const int v = (t < NB_SCAN) ? bsum[t] : 0;
    sh[t] = v;
    __syncthreads();
#pragma unroll
    for (int s = 1; s < 256; s <<= 1) {
        int add = (t >= s) ? sh[t - s] : 0;
        __syncthreads();
        sh[t] += add;
        __syncthreads();
    }
    if (t < NB_SCAN) bbase[t] = sh[t] - v;  // exclusive
}

// ---------------- scan phase C: local scan + offset -> rowptr, cur ----------------
__global__ __launch_bounds__(256) void k_scanfin(const int* __restrict__ deg,
                                                 const int* __restrict__ bbase,
                                                 int* __restrict__ rowptr,
                                                 int* __restrict__ cur) {
    __shared__ int sh[256];
    const int t = threadIdx.x;
    const int i = blockIdx.x * 256 + t;
    const int v = (i < NN) ? deg[i] : 0;
    sh[t] = v;
    __syncthreads();
#pragma unroll
    for (int s = 1; s < 256; s <<= 1) {
        int add = (t >= s) ? sh[t - s] : 0;
        __syncthreads();
        sh[t] += add;
        __syncthreads();
    }
    const int incl = sh[t] + bbase[blockIdx.x];
    if (i < NN) {
        const int excl = incl - v;
        rowptr[i] = excl;
        cur[i] = excl;
        if (i == NN - 1) rowptr[NN] = incl;
    }
}

// ---------------- CSR build: fill edge sources ----------------
__global__ void k_fill(const int* __restrict__ src, const int* __restrict__ dst,
                       int* __restrict__ cur, int* __restrict__ esrc) {
    const int e = blockIdx.x * 256 + threadIdx.x;
    const int p = atomicAdd(&cur[dst[e]], 1);
    esrc[p] = src[e];
}

// ---------------- gather-aggregate: H[i] = Z[i] + sum_{j->i} Z[j] ----------------
__global__ __launch_bounds__(256) void k_agg(const float* __restrict__ Z,
                                             const int* __restrict__ rowptr,
                                             const int* __restrict__ esrc,
                                             float* __restrict__ H) {
    const int node = blockIdx.x * 2 + (threadIdx.x >> 7);
    const int col = threadIdx.x & 127;
    const int start = rowptr[node], end = rowptr[node + 1];
    float acc = Z[(size_t)node * HD + col];
    int k = start;
    for (; k + 1 < end; k += 2) {
        const int s0 = esrc[k], s1 = esrc[k + 1];
        const float v0 = Z[(size_t)s0 * HD + col];
        const float v1 = Z[(size_t)s1 * HD + col];
        acc += v0 + v1;
    }
    if (k < end) acc += Z[(size_t)esrc[k] * HD + col];
    H[(size_t)node * HD + col] = acc;
}

// ---------------- MFMA GEMM (bf16x3 split): C = act(A @ W + b) ----------------
// Both A and W split into bf16 hi+lo; compute ah*wh + ah*wl + al*wh (drop al*wl <= 2^-16).
// Effective input precision ~fp32 -> survives BN's 1/sigma amplification (R5 post-mortem).
// Wt staged transposed in LDS ([n][k], stride 136 shorts -> 16B-aligned b128, 2-way conflicts only).
// Fragment layouts (learn_hip m89/m91/m120): A[m=lane&15][k=(lane>>4)*8+j]; B[n=lane&15][k same];
// C/D: col=lane&15, row=(lane>>4)*4+reg.
template <int ACT>
__global__ __launch_bounds__(256) void k_gemm_mfma(const float* __restrict__ A,
                                                   const float* __restrict__ W,
                                                   const float* __restrict__ bias,
                                                   float* __restrict__ C) {
    __shared__ __bf16 Wth[128 * 136];  // 34816 B, W^T hi
    __shared__ __bf16 Wtl[128 * 136];  // 34816 B, W^T lo
    const int tid = threadIdx.x;
    for (int i = tid; i < 128 * 32; i += 256) {
        const int k = i >> 5;
        const int n4 = (i & 31) << 2;
        const float4 w = *(const float4*)&W[k * HD + n4];
        const float wf[4] = {w.x, w.y, w.z, w.w};
#pragma unroll
        for (int j = 0; j < 4; ++j) {
            const __bf16 h = (__bf16)wf[j];
            Wth[(n4 + j) * 136 + k] = h;
            Wtl[(n4 + j) * 136 + k] = (__bf16)(wf[j] - (float)h);
        }
    }
    __syncthreads();

    const int wid = tid >> 6, lane = tid & 63;
    const int lq = lane >> 4, lm = lane & 15;
    const int rowbase = blockIdx.x * 128 + wid * 32;
    const int r0 = min(rowbase + lm, NN - 1);       // clamped load rows (garbage rows never stored)
    const int r1 = min(rowbase + 16 + lm, NN - 1);

    floatx4 acc[2][8];
#pragma unroll
    for (int i = 0; i < 2; ++i)
#pragma unroll
        for (int j = 0; j < 8; ++j) acc[i][j] = (floatx4){0.f, 0.f, 0.f, 0.f};

#pragma unroll
    for (int ks = 0; ks < 4; ++ks) {
        const int kk = ks * 32 + lq * 8;
        const float4 a0a = *(const float4*)&A[(size_t)r0 * HD + kk];
        const float4 a0b = *(const float4*)&A[(size_t)r0 * HD + kk + 4];
        const float4 a1a = *(const float4*)&A[(size_t)r1 * HD + kk];
        const float4 a1b = *(const float4*)&A[(size_t)r1 * HD + kk + 4];
        bf16x8 ah0, al0, ah1, al1;
        {
            const float f0[8] = {a0a.x, a0a.y, a0a.z, a0a.w, a0b.x, a0b.y, a0b.z, a0b.w};
            const float f1[8] = {a1a.x, a1a.y, a1a.z, a1a.w, a1b.x, a1b.y, a1b.z, a1b.w};
#pragma unroll
            for (int j = 0; j < 8; ++j) {
                const __bf16 h0 = (__bf16)f0[j];
                ah0[j] = h0;
                al0[j] = (__bf16)(f0[j] - (float)h0);
                const __bf16 h1 = (__bf16)f1[j];
                ah1[j] = h1;
                al1[j] = (__bf16)(f1[j] - (float)h1);
            }
        }
#pragma unroll
        for (int ct = 0; ct < 8; ++ct) {
            const bf16x8 bh = *(const bf16x8*)&Wth[(ct * 16 + lm) * 136 + kk];
            const bf16x8 bl = *(const bf16x8*)&Wtl[(ct * 16 + lm) * 136 + kk];
            acc[0][ct] = __builtin_amdgcn_mfma_f32_16x16x32_bf16(al0, bh, acc[0][ct], 0, 0, 0);
            acc[0][ct] = __builtin_amdgcn_mfma_f32_16x16x32_bf16(ah0, bl, acc[0][ct], 0, 0, 0);
            acc[0][ct] = __builtin_amdgcn_mfma_f32_16x16x32_bf16(ah0, bh, acc[0][ct], 0, 0, 0);
            acc[1][ct] = __builtin_amdgcn_mfma_f32_16x16x32_bf16(al1, bh, acc[1][ct], 0, 0, 0);
            acc[1][ct] = __builtin_amdgcn_mfma_f32_16x16x32_bf16(ah1, bl, acc[1][ct], 0, 0, 0);
            acc[1][ct] = __builtin_amdgcn_mfma_f32_16x16x32_bf16(ah1, bh, acc[1][ct], 0, 0, 0);
        }
    }

#pragma unroll
    for (int rt = 0; rt < 2; ++rt) {
#pragma unroll
        for (int ct = 0; ct < 8; ++ct) {
            const int col = ct * 16 + lm;
            const float bcol = bias[col];
            const int rw = rowbase + rt * 16 + lq * 4;
            const floatx4 v = acc[rt][ct];
#pragma unroll
            for (int r = 0; r < 4; ++r) {
                float y = v[r] + bcol;
                if (ACT) y = fmaxf(y, 0.f);
                if (rw + r < NN) C[(size_t)(rw + r) * HD + col] = y;
            }
        }
    }
}

// ---------------- per-column sum / sumsq ----------------
__global__ void k_colstats(const float* __restrict__ X, float* __restrict__ sum,
                           float* __restrict__ sumsq) {
    __shared__ float sh[128], shq[128];
    const int col = threadIdx.x & 127, half = threadIdx.x >> 7;
    const int r0 = blockIdx.x * 256;
    const int r1 = min(r0 + 256, NN);
    float s = 0.f, q = 0.f;
    for (int r = r0 + half; r < r1; r += 2) {
        const float v = X[(size_t)r * HD + col];
        s += v;
        q = fmaf(v, v, q);
    }
    if (half) { sh[col] = s; shq[col] = q; }
    __syncthreads();
    if (!half) {
        atomicAdd(&sum[col], s + sh[col]);
        atomicAdd(&sumsq[col], q + shq[col]);
    }
}

// ---------------- BN finalize ----------------
__global__ void k_bnfin(const float* __restrict__ sum, const float* __restrict__ sumsq,
                        const float* __restrict__ gamma, const float* __restrict__ beta,
                        float* __restrict__ scale, float* __restrict__ shift) {
    const int c = threadIdx.x;
    const float mean = sum[c] * (1.f / NN);
    const float var = sumsq[c] * (1.f / NN) - mean * mean;
    const float sc = gamma[c] * rsqrtf(var + BN_EPS);
    scale[c] = sc;
    shift[c] = beta[c] - mean * sc;
}

// ---------------- BN apply (+ optional PReLU), in-place capable ----------------
template <int PRELU>
__global__ void k_bnapply(const float* __restrict__ X, const float* __restrict__ scale,
                          const float* __restrict__ shift, float* __restrict__ Y,
                          const float* __restrict__ pa) {
    const int i = blockIdx.x * 256 + threadIdx.x;
    const int c = i & 127;
    float v = fmaf(X[i], scale[c], shift[c]);
    if (PRELU) {
        const float a = pa[0];
        if (v < 0.f) v = a * v;
    }
    Y[i] = v;
}

extern "C" void kernel_launch(void* const* d_in, const int* in_sizes, int n_in,
                              void* d_out, int out_size, void* d_ws, size_t ws_size,
                              hipStream_t stream) {
    const float* x = (const float*)d_in[0];
    const int* ei = (const int*)d_in[1];
    const float* w0a = (const float*)d_in[2];
    const float* b0a = (const float*)d_in[3];
    const float* w0b = (const float*)d_in[4];
    const float* b0b = (const float*)d_in[5];
    const float* w1a = (const float*)d_in[6];
    const float* b1a = (const float*)d_in[7];
    const float* w1b = (const float*)d_in[8];
    const float* b1b = (const float*)d_in[9];
    const float* bng = (const float*)d_in[10];
    const float* bnb = (const float*)d_in[11];
    const float* pw  = (const float*)d_in[12];
    const float* pb  = (const float*)d_in[13];
    const float* pbng = (const float*)d_in[14];
    const float* pbnb = (const float*)d_in[15];
    const float* pa = (const float*)d_in[16];

    float* outZ = (float*)d_out;                    // (NN,128) f32 — z
    float* outP = outZ + (size_t)NN * HD;           // (NN,128) f32 — p (also MLP temp)

    float* ws = (float*)d_ws;
    float* bufH = ws;                               // (NN,128) f32 — aggregate
    float* st = bufH + (size_t)NN * HD;             // 1024 floats of stats
    int* deg = (int*)(st + 1024);                   // NN
    int* rowptr = deg + NN;                         // NN+1 (+pad)
    int* cur = rowptr + NN + 64;                    // NN
    int* esrc = cur + NN;                           // NE
    int* bsum = esrc + NE;                          // 256
    int* bbase = bsum + 256;                        // 256

    const int* srcv = ei;
    const int* dstv = ei + NE;

    const int EB = NE / 256;                        // 3125 edge blocks
    const int NB = NB_SCAN;                         // 196 node blocks
    const int EL1 = (NN * HD) / 256;                // 25000 elementwise blocks
    const int GB = (NN + 127) / 128;                // 391 GEMM blocks

    // ---- CSR build (dst-sorted) + stat zeroing ----
    k_zero_f<<<4, 256, 0, stream>>>(st, 1024);
    k_zero_i<<<NB, 256, 0, stream>>>(deg, NN);
    k_hist<<<EB, 256, 0, stream>>>(dstv, deg);
    k_blocksum<<<NB, 256, 0, stream>>>(deg, bsum);
    k_scanpart<<<1, 256, 0, stream>>>(bsum, bbase);
    k_scanfin<<<NB, 256, 0, stream>>>(deg, bbase, rowptr, cur);
    k_fill<<<EB, 256, 0, stream>>>(srcv, dstv, cur, esrc);

    // ---- GIN layer 0 ----
    k_agg<<<NN / 2, 256, 0, stream>>>(x, rowptr, esrc, bufH);
    k_gemm_mfma<1><<<GB, 256, 0, stream>>>(bufH, w0a, b0a, outP);
    k_gemm_mfma<1><<<GB, 256, 0, stream>>>(outP, w0b, b0b, outZ);   // z1

    // ---- GIN layer 1 ----
    k_agg<<<NN / 2, 256, 0, stream>>>(outZ, rowptr, esrc, bufH);
    k_gemm_mfma<1><<<GB, 256, 0, stream>>>(bufH, w1a, b1a, outP);
    k_gemm_mfma<1><<<GB, 256, 0, stream>>>(outP, w1b, b1b, outZ);   // z2

    // ---- encoder BatchNorm -> z output (in place) ----
    k_colstats<<<NB, 256, 0, stream>>>(outZ, st + 0, st + 128);
    k_bnfin<<<1, 128, 0, stream>>>(st + 0, st + 128, bng, bnb, st + 256, st + 384);
    k_bnapply<0><<<EL1, 256, 0, stream>>>(outZ, st + 256, st + 384, outZ, pa);

    // ---- projection head: linear -> BN -> PReLU -> p output (in place) ----
    k_gemm_mfma<0><<<GB, 256, 0, stream>>>(outZ, pw, pb, outP);
    k_colstats<<<NB, 256, 0, stream>>>(outP, st + 512, st + 640);
    k_bnfin<<<1, 128, 0, stream>>>(st + 512, st + 640, pbng, pbnb, st + 768, st + 896);
    k_bnapply<1><<<EL1, 256, 0, stream>>>(outP, st + 768, st + 896, outP, pa);
}

// Round 7
// 539.132 us; speedup vs baseline: 2.0619x; 1.1408x over previous
//
#include <hip/hip_runtime.h>
#include <hip/hip_bf16.h>

#define NN 50000
#define NE 800000
#define HD 128
#define BN_EPS 1e-5f
#define NB_SCAN 196  // ceil(NN/256)

typedef __attribute__((ext_vector_type(8))) __bf16 bf16x8;
typedef __attribute__((ext_vector_type(4))) float floatx4;

// ---------------- zero helpers ----------------
__global__ void k_zero_f(float* __restrict__ p, int n) {
    const int i = blockIdx.x * 256 + threadIdx.x;
    if (i < n) p[i] = 0.f;
}
__global__ void k_zero_i(int* __restrict__ p, int n) {
    const int i = blockIdx.x * 256 + threadIdx.x;
    if (i < n) p[i] = 0;
}

// ---------------- CSR build: histogram of dst ----------------
__global__ void k_hist(const int* __restrict__ dst, int* __restrict__ deg) {
    const int e = blockIdx.x * 256 + threadIdx.x;
    atomicAdd(&deg[dst[e]], 1);
}

// ---------------- scan phase A: per-block sums of deg ----------------
__global__ __launch_bounds__(256) void k_blocksum(const int* __restrict__ deg,
                                                  int* __restrict__ bsum) {
    __shared__ int sh[256];
    const int t = threadIdx.x;
    const int i = blockIdx.x * 256 + t;
    sh[t] = (i < NN) ? deg[i] : 0;
    __syncthreads();
#pragma unroll
    for (int s = 128; s > 0; s >>= 1) {
        if (t < s) sh[t] += sh[t + s];
        __syncthreads();
    }
    if (t == 0) bsum[blockIdx.x] = sh[0];
}

// ---------------- scan phase B: exclusive scan of block sums (1 block) ----------------
__global__ __launch_bounds__(256) void k_scanpart(const int* __restrict__ bsum,
                                                  int* __restrict__ bbase) {
    __shared__ int sh[256];
    const int t = threadIdx.x;
    const int v = (t < NB_SCAN) ? bsum[t] : 0;
    sh[t] = v;
    __syncthreads();
#pragma unroll
    for (int s = 1; s < 256; s <<= 1) {
        int add = (t >= s) ? sh[t - s] : 0;
        __syncthreads();
        sh[t] += add;
        __syncthreads();
    }
    if (t < NB_SCAN) bbase[t] = sh[t] - v;  // exclusive
}

// ---------------- scan phase C: local scan + offset -> rowptr, cur ----------------
__global__ __launch_bounds__(256) void k_scanfin(const int* __restrict__ deg,
                                                 const int* __restrict__ bbase,
                                                 int* __restrict__ rowptr,
                                                 int* __restrict__ cur) {
    __shared__ int sh[256];
    const int t = threadIdx.x;
    const int i = blockIdx.x * 256 + t;
    const int v = (i < NN) ? deg[i] : 0;
    sh[t] = v;
    __syncthreads();
#pragma unroll
    for (int s = 1; s < 256; s <<= 1) {
        int add = (t >= s) ? sh[t - s] : 0;
        __syncthreads();
        sh[t] += add;
        __syncthreads();
    }
    const int incl = sh[t] + bbase[blockIdx.x];
    if (i < NN) {
        const int excl = incl - v;
        rowptr[i] = excl;
        cur[i] = excl;
        if (i == NN - 1) rowptr[NN] = incl;
    }
}

// ---------------- CSR build: fill edge sources ----------------
__global__ void k_fill(const int* __restrict__ src, const int* __restrict__ dst,
                       int* __restrict__ cur, int* __restrict__ esrc) {
    const int e = blockIdx.x * 256 + threadIdx.x;
    const int p = atomicAdd(&cur[dst[e]], 1);
    esrc[p] = src[e];
}

// ---------------- gather-aggregate: H[i] = Z[i] + sum_{j->i} Z[j] ----------------
// 32-lane group per node, float4 per lane, 4-edge unroll: 4x fewer memory
// instructions than the scalar version, 4 independent 16B loads in flight.
__global__ __launch_bounds__(256) void k_agg(const float* __restrict__ Z,
                                             const int* __restrict__ rowptr,
                                             const int* __restrict__ esrc,
                                             float* __restrict__ H) {
    const int g = threadIdx.x >> 5;          // group 0..7
    const int lc = threadIdx.x & 31;
    const int node = blockIdx.x * 8 + g;
    const int c4 = lc * 4;
    const int start = rowptr[node], end = rowptr[node + 1];
    float4 acc = *(const float4*)&Z[(size_t)node * HD + c4];
    int k = start;
    for (; k + 4 <= end; k += 4) {
        const int s0 = esrc[k], s1 = esrc[k + 1], s2 = esrc[k + 2], s3 = esrc[k + 3];
        const float4 v0 = *(const float4*)&Z[(size_t)s0 * HD + c4];
        const float4 v1 = *(const float4*)&Z[(size_t)s1 * HD + c4];
        const float4 v2 = *(const float4*)&Z[(size_t)s2 * HD + c4];
        const float4 v3 = *(const float4*)&Z[(size_t)s3 * HD + c4];
        acc.x += v0.x + v1.x + v2.x + v3.x;
        acc.y += v0.y + v1.y + v2.y + v3.y;
        acc.z += v0.z + v1.z + v2.z + v3.z;
        acc.w += v0.w + v1.w + v2.w + v3.w;
    }
    for (; k < end; ++k) {
        const int s = esrc[k];
        const float4 v = *(const float4*)&Z[(size_t)s * HD + c4];
        acc.x += v.x; acc.y += v.y; acc.z += v.z; acc.w += v.w;
    }
    *(float4*)&H[(size_t)node * HD + c4] = acc;
}

// ---------------- MFMA GEMM (bf16x3 split): C = act(A @ W + b) ----------------
// Both A and W split into bf16 hi+lo; compute ah*wh + ah*wl + al*wh (drop al*wl <= 2^-16).
// Effective input precision ~fp32 -> survives BN's 1/sigma amplification (R5 post-mortem).
// Wt staged transposed in LDS ([n][k], stride 136 shorts -> 16B-aligned b128, 2-way conflicts only).
// Fragment layouts (learn_hip m89/m91/m120): A[m=lane&15][k=(lane>>4)*8+j]; B[n=lane&15][k same];
// C/D: col=lane&15, row=(lane>>4)*4+reg.
template <int ACT>
__global__ __launch_bounds__(256) void k_gemm_mfma(const float* __restrict__ A,
                                                   const float* __restrict__ W,
                                                   const float* __restrict__ bias,
                                                   float* __restrict__ C) {
    __shared__ __bf16 Wth[128 * 136];  // 34816 B, W^T hi
    __shared__ __bf16 Wtl[128 * 136];  // 34816 B, W^T lo
    const int tid = threadIdx.x;
    for (int i = tid; i < 128 * 32; i += 256) {
        const int k = i >> 5;
        const int n4 = (i & 31) << 2;
        const float4 w = *(const float4*)&W[k * HD + n4];
        const float wf[4] = {w.x, w.y, w.z, w.w};
#pragma unroll
        for (int j = 0; j < 4; ++j) {
            const __bf16 h = (__bf16)wf[j];
            Wth[(n4 + j) * 136 + k] = h;
            Wtl[(n4 + j) * 136 + k] = (__bf16)(wf[j] - (float)h);
        }
    }
    __syncthreads();

    const int wid = tid >> 6, lane = tid & 63;
    const int lq = lane >> 4, lm = lane & 15;
    const int rowbase = blockIdx.x * 128 + wid * 32;
    const int r0 = min(rowbase + lm, NN - 1);       // clamped load rows (garbage rows never stored)
    const int r1 = min(rowbase + 16 + lm, NN - 1);

    floatx4 acc[2][8];
#pragma unroll
    for (int i = 0; i < 2; ++i)
#pragma unroll
        for (int j = 0; j < 8; ++j) acc[i][j] = (floatx4){0.f, 0.f, 0.f, 0.f};

#pragma unroll
    for (int ks = 0; ks < 4; ++ks) {
        const int kk = ks * 32 + lq * 8;
        const float4 a0a = *(const float4*)&A[(size_t)r0 * HD + kk];
        const float4 a0b = *(const float4*)&A[(size_t)r0 * HD + kk + 4];
        const float4 a1a = *(const float4*)&A[(size_t)r1 * HD + kk];
        const float4 a1b = *(const float4*)&A[(size_t)r1 * HD + kk + 4];
        bf16x8 ah0, al0, ah1, al1;
        {
            const float f0[8] = {a0a.x, a0a.y, a0a.z, a0a.w, a0b.x, a0b.y, a0b.z, a0b.w};
            const float f1[8] = {a1a.x, a1a.y, a1a.z, a1a.w, a1b.x, a1b.y, a1b.z, a1b.w};
#pragma unroll
            for (int j = 0; j < 8; ++j) {
                const __bf16 h0 = (__bf16)f0[j];
                ah0[j] = h0;
                al0[j] = (__bf16)(f0[j] - (float)h0);
                const __bf16 h1 = (__bf16)f1[j];
                ah1[j] = h1;
                al1[j] = (__bf16)(f1[j] - (float)h1);
            }
        }
#pragma unroll
        for (int ct = 0; ct < 8; ++ct) {
            const bf16x8 bh = *(const bf16x8*)&Wth[(ct * 16 + lm) * 136 + kk];
            const bf16x8 bl = *(const bf16x8*)&Wtl[(ct * 16 + lm) * 136 + kk];
            acc[0][ct] = __builtin_amdgcn_mfma_f32_16x16x32_bf16(al0, bh, acc[0][ct], 0, 0, 0);
            acc[0][ct] = __builtin_amdgcn_mfma_f32_16x16x32_bf16(ah0, bl, acc[0][ct], 0, 0, 0);
            acc[0][ct] = __builtin_amdgcn_mfma_f32_16x16x32_bf16(ah0, bh, acc[0][ct], 0, 0, 0);
            acc[1][ct] = __builtin_amdgcn_mfma_f32_16x16x32_bf16(al1, bh, acc[1][ct], 0, 0, 0);
            acc[1][ct] = __builtin_amdgcn_mfma_f32_16x16x32_bf16(ah1, bl, acc[1][ct], 0, 0, 0);
            acc[1][ct] = __builtin_amdgcn_mfma_f32_16x16x32_bf16(ah1, bh, acc[1][ct], 0, 0, 0);
        }
    }

#pragma unroll
    for (int rt = 0; rt < 2; ++rt) {
#pragma unroll
        for (int ct = 0; ct < 8; ++ct) {
            const int col = ct * 16 + lm;
            const float bcol = bias[col];
            const int rw = rowbase + rt * 16 + lq * 4;
            const floatx4 v = acc[rt][ct];
#pragma unroll
            for (int r = 0; r < 4; ++r) {
                float y = v[r] + bcol;
                if (ACT) y = fmaxf(y, 0.f);
                if (rw + r < NN) C[(size_t)(rw + r) * HD + col] = y;
            }
        }
    }
}

// ---------------- per-column sum / sumsq ----------------
__global__ void k_colstats(const float* __restrict__ X, float* __restrict__ sum,
                           float* __restrict__ sumsq) {
    __shared__ float sh[128], shq[128];
    const int col = threadIdx.x & 127, half = threadIdx.x >> 7;
    const int r0 = blockIdx.x * 256;
    const int r1 = min(r0 + 256, NN);
    float s = 0.f, q = 0.f;
    for (int r = r0 + half; r < r1; r += 2) {
        const float v = X[(size_t)r * HD + col];
        s += v;
        q = fmaf(v, v, q);
    }
    if (half) { sh[col] = s; shq[col] = q; }
    __syncthreads();
    if (!half) {
        atomicAdd(&sum[col], s + sh[col]);
        atomicAdd(&sumsq[col], q + shq[col]);
    }
}

// ---------------- BN finalize ----------------
__global__ void k_bnfin(const float* __restrict__ sum, const float* __restrict__ sumsq,
                        const float* __restrict__ gamma, const float* __restrict__ beta,
                        float* __restrict__ scale, float* __restrict__ shift) {
    const int c = threadIdx.x;
    const float mean = sum[c] * (1.f / NN);
    const float var = sumsq[c] * (1.f / NN) - mean * mean;
    const float sc = gamma[c] * rsqrtf(var + BN_EPS);
    scale[c] = sc;
    shift[c] = beta[c] - mean * sc;
}

// ---------------- BN apply (+ optional PReLU), float4, in-place capable ----------------
template <int PRELU>
__global__ void k_bnapply(const float* __restrict__ X, const float* __restrict__ scale,
                          const float* __restrict__ shift, float* __restrict__ Y,
                          const float* __restrict__ pa) {
    const int i4 = (blockIdx.x * 256 + threadIdx.x) * 4;
    const int c = i4 & 127;
    const float4 sc = *(const float4*)&scale[c];
    const float4 sh = *(const float4*)&shift[c];
    const float4 v = *(const float4*)&X[i4];
    float4 y;
    y.x = fmaf(v.x, sc.x, sh.x);
    y.y = fmaf(v.y, sc.y, sh.y);
    y.z = fmaf(v.z, sc.z, sh.z);
    y.w = fmaf(v.w, sc.w, sh.w);
    if (PRELU) {
        const float a = pa[0];
        if (y.x < 0.f) y.x *= a;
        if (y.y < 0.f) y.y *= a;
        if (y.z < 0.f) y.z *= a;
        if (y.w < 0.f) y.w *= a;
    }
    *(float4*)&Y[i4] = y;
}

extern "C" void kernel_launch(void* const* d_in, const int* in_sizes, int n_in,
                              void* d_out, int out_size, void* d_ws, size_t ws_size,
                              hipStream_t stream) {
    const float* x = (const float*)d_in[0];
    const int* ei = (const int*)d_in[1];
    const float* w0a = (const float*)d_in[2];
    const float* b0a = (const float*)d_in[3];
    const float* w0b = (const float*)d_in[4];
    const float* b0b = (const float*)d_in[5];
    const float* w1a = (const float*)d_in[6];
    const float* b1a = (const float*)d_in[7];
    const float* w1b = (const float*)d_in[8];
    const float* b1b = (const float*)d_in[9];
    const float* bng = (const float*)d_in[10];
    const float* bnb = (const float*)d_in[11];
    const float* pw  = (const float*)d_in[12];
    const float* pb  = (const float*)d_in[13];
    const float* pbng = (const float*)d_in[14];
    const float* pbnb = (const float*)d_in[15];
    const float* pa = (const float*)d_in[16];

    float* outZ = (float*)d_out;                    // (NN,128) f32 — z
    float* outP = outZ + (size_t)NN * HD;           // (NN,128) f32 — p (also MLP temp)

    float* ws = (float*)d_ws;
    float* bufH = ws;                               // (NN,128) f32 — aggregate
    float* st = bufH + (size_t)NN * HD;             // 1024 floats of stats
    int* deg = (int*)(st + 1024);                   // NN
    int* rowptr = deg + NN;                         // NN+1 (+pad)
    int* cur = rowptr + NN + 64;                    // NN
    int* esrc = cur + NN;                           // NE
    int* bsum = esrc + NE;                          // 256
    int* bbase = bsum + 256;                        // 256

    const int* srcv = ei;
    const int* dstv = ei + NE;

    const int EB = NE / 256;                        // 3125 edge blocks
    const int NB = NB_SCAN;                         // 196 node blocks
    const int ELV = (NN * HD) / (256 * 4);          // 6250 float4 elementwise blocks
    const int GB = (NN + 127) / 128;                // 391 GEMM blocks
    const int AB = NN / 8;                          // 6250 agg blocks

    // ---- CSR build (dst-sorted) + stat zeroing ----
    k_zero_f<<<4, 256, 0, stream>>>(st, 1024);
    k_zero_i<<<NB, 256, 0, stream>>>(deg, NN);
    k_hist<<<EB, 256, 0, stream>>>(dstv, deg);
    k_blocksum<<<NB, 256, 0, stream>>>(deg, bsum);
    k_scanpart<<<1, 256, 0, stream>>>(bsum, bbase);
    k_scanfin<<<NB, 256, 0, stream>>>(deg, bbase, rowptr, cur);
    k_fill<<<EB, 256, 0, stream>>>(srcv, dstv, cur, esrc);

    // ---- GIN layer 0 ----
    k_agg<<<AB, 256, 0, stream>>>(x, rowptr, esrc, bufH);
    k_gemm_mfma<1><<<GB, 256, 0, stream>>>(bufH, w0a, b0a, outP);
    k_gemm_mfma<1><<<GB, 256, 0, stream>>>(outP, w0b, b0b, outZ);   // z1

    // ---- GIN layer 1 ----
    k_agg<<<AB, 256, 0, stream>>>(outZ, rowptr, esrc, bufH);
    k_gemm_mfma<1><<<GB, 256, 0, stream>>>(bufH, w1a, b1a, outP);
    k_gemm_mfma<1><<<GB, 256, 0, stream>>>(outP, w1b, b1b, outZ);   // z2

    // ---- encoder BatchNorm -> z output (in place) ----
    k_colstats<<<NB, 256, 0, stream>>>(outZ, st + 0, st + 128);
    k_bnfin<<<1, 128, 0, stream>>>(st + 0, st + 128, bng, bnb, st + 256, st + 384);
    k_bnapply<0><<<ELV, 256, 0, stream>>>(outZ, st + 256, st + 384, outZ, pa);

    // ---- projection head: linear -> BN -> PReLU -> p output (in place) ----
    k_gemm_mfma<0><<<GB, 256, 0, stream>>>(outZ, pw, pb, outP);
    k_colstats<<<NB, 256, 0, stream>>>(outP, st + 512, st + 640);
    k_bnfin<<<1, 128, 0, stream>>>(st + 512, st + 640, pbng, pbnb, st + 768, st + 896);
    k_bnapply<1><<<ELV, 256, 0, stream>>>(outP, st + 768, st + 896, outP, pa);
}